// Round 2
// baseline (418.707 us; speedup 1.0000x reference)
//
#include <hip/hip_runtime.h>
#include <hip/hip_bf16.h>
#include <hip/hip_fp16.h>

typedef _Float16 half_t;
typedef _Float16 h8 __attribute__((ext_vector_type(8)));
typedef _Float16 h4v __attribute__((ext_vector_type(4)));
typedef _Float16 h2v __attribute__((ext_vector_type(2)));
typedef float f4v __attribute__((ext_vector_type(4)));

union H8u { h8 v; h2v h2[4]; _Float16 e[8]; };
union H4u { h4v v; h2v h2[2]; _Float16 e[4]; };

static inline int cdiv(long a, long b) { return (int)((a + b - 1) / b); }

__device__ __forceinline__ void fma4(float4& a, float s, const float4& w) {
    a.x += s * w.x; a.y += s * w.y; a.z += s * w.z; a.w += s * w.w;
}

__device__ __forceinline__ h8 hmax8(h8 a, h8 b) {
#if __has_builtin(__builtin_elementwise_max)
    return __builtin_elementwise_max(a, b);
#else
    h8 r;
#pragma unroll
    for (int j = 0; j < 8; ++j) r[j] = (a[j] > b[j]) ? a[j] : b[j];
    return r;
#endif
}
__device__ __forceinline__ h4v hmax4(h4v a, h4v b) {
#if __has_builtin(__builtin_elementwise_max)
    return __builtin_elementwise_max(a, b);
#else
    h4v r;
#pragma unroll
    for (int j = 0; j < 4; ++j) r[j] = (a[j] > b[j]) ? a[j] : b[j];
    return r;
#endif
}

__device__ __forceinline__ float dot2acc(h2v a, h2v b, float c) {
#if __has_builtin(__builtin_amdgcn_fdot2)
    return __builtin_amdgcn_fdot2(a, b, c, false);
#else
    return c + (float)a.x * (float)b.x + (float)a.y * (float)b.y;
#endif
}

// ---------------- emb GEMM (fp32 compute, fp16 out) ----------------

template <int K4, int C4, int R>
__global__ __launch_bounds__(256) void gemm_t_h(
        const float* __restrict__ X, const float* __restrict__ W,
        const float* __restrict__ bias, half_t* __restrict__ Y,
        int Nr, int relu) {
    int idx = blockIdx.x * blockDim.x + threadIdx.x;
    int total = (Nr / R) * C4;
    if (idx >= total) return;
    int c4 = idx % C4;
    int n0 = (idx / C4) * R;
    const float4* __restrict__ Wv = (const float4*)W;
    const float4* __restrict__ Xv = (const float4*)X;
    float4 acc[R];
    float4 binit = bias ? ((const float4*)bias)[c4] : make_float4(0.f, 0.f, 0.f, 0.f);
#pragma unroll
    for (int r = 0; r < R; ++r) acc[r] = binit;
#pragma unroll 4
    for (int k4 = 0; k4 < K4; ++k4) {
        float4 w0 = Wv[(size_t)(4 * k4 + 0) * C4 + c4];
        float4 w1 = Wv[(size_t)(4 * k4 + 1) * C4 + c4];
        float4 w2 = Wv[(size_t)(4 * k4 + 2) * C4 + c4];
        float4 w3 = Wv[(size_t)(4 * k4 + 3) * C4 + c4];
#pragma unroll
        for (int r = 0; r < R; ++r) {
            float4 xv = Xv[(size_t)(n0 + r) * K4 + k4];
            fma4(acc[r], xv.x, w0); fma4(acc[r], xv.y, w1);
            fma4(acc[r], xv.z, w2); fma4(acc[r], xv.w, w3);
        }
    }
#pragma unroll
    for (int r = 0; r < R; ++r) {
        float4 o = acc[r];
        if (relu) {
            o.x = fmaxf(o.x, 0.f); o.y = fmaxf(o.y, 0.f);
            o.z = fmaxf(o.z, 0.f); o.w = fmaxf(o.w, 0.f);
        }
        h4v oh; oh.x = (half_t)o.x; oh.y = (half_t)o.y; oh.z = (half_t)o.z; oh.w = (half_t)o.w;
        ((h4v*)Y)[(size_t)(n0 + r) * C4 + c4] = oh;
    }
}

// ---------------- weight transpose+convert + att convert ----------------

__global__ void wtrans(const float* __restrict__ c1l, const float* __restrict__ c1r,
                       const float* __restrict__ c2l, const float* __restrict__ c2r,
                       const float* __restrict__ ggl, const float* __restrict__ ggr,
                       const float* __restrict__ at1, const float* __restrict__ at2,
                       const float* __restrict__ atg, half_t* __restrict__ dst) {
    int idx = blockIdx.x * blockDim.x + threadIdx.x;
    if (idx >= 49440) return;
    if (idx >= 49152) {
        int j = idx - 49152;
        float v = (j < 128) ? at1[j] : (j < 256) ? at2[j - 128] : atg[j - 256];
        dst[idx] = (half_t)v;
        return;
    }
    const float* src; int K, loc;
    if (idx < 8192) {
        K = 32;
        if (idx < 4096) { src = c1l; loc = idx; } else { src = c1r; loc = idx - 4096; }
        int k = loc % K, c = loc / K;
        dst[idx] = (half_t)src[k * 128 + c];
    } else if (idx < 40960) {
        K = 128;
        if (idx < 24576) { src = c2l; loc = idx - 8192; } else { src = c2r; loc = idx - 24576; }
        int k = loc % K, c = loc / K;
        dst[idx] = (half_t)src[k * 128 + c];
    } else {
        K = 128;
        if (idx < 45056) { src = ggl; loc = idx - 40960; } else { src = ggr; loc = idx - 45056; }
        int k = loc % K, c = loc / K;
        dst[idx] = (half_t)src[k * 32 + c];
    }
}

// ---------------- MFMA dual GEMM ----------------

template <int K, int C1>
__global__ __launch_bounds__(256) void mfma_dual(
        const half_t* __restrict__ Xh,
        const half_t* __restrict__ W1t, const half_t* __restrict__ W2t,
        half_t* __restrict__ Y1, half_t* __restrict__ Y2, int Nr) {
    constexpr int KT = K / 32;
    constexpr int NBC = (2 * C1) / 64;
    int wave = threadIdx.x >> 6, lane = threadIdx.x & 63;
    int bCol = blockIdx.x % NBC;
    int bRow = blockIdx.x / NBC;
    int rowBase = bRow * 128 + wave * 32;
    int colBase = bCol * 64;
    int m = lane & 15, quad = lane >> 4;

    f4v acc[2][4] = {};

    const half_t* bptr[4];
#pragma unroll
    for (int nt = 0; nt < 4; ++nt) {
        int gc = colBase + nt * 16 + m;
        bptr[nt] = (gc < C1) ? (W1t + (size_t)gc * K) : (W2t + (size_t)(gc - C1) * K);
    }
    int r0 = rowBase + m, r1 = rowBase + 16 + m;
    int r0c = (r0 < Nr) ? r0 : (Nr - 1);
    int r1c = (r1 < Nr) ? r1 : (Nr - 1);
    const half_t* a0p = Xh + (size_t)r0c * K + quad * 8;
    const half_t* a1p = Xh + (size_t)r1c * K + quad * 8;

#pragma unroll
    for (int kk = 0; kk < KT; ++kk) {
        h8 a0 = *(const h8*)(a0p + kk * 32);
        h8 a1 = *(const h8*)(a1p + kk * 32);
#pragma unroll
        for (int nt = 0; nt < 4; ++nt) {
            h8 b = *(const h8*)(bptr[nt] + kk * 32 + quad * 8);
            acc[0][nt] = __builtin_amdgcn_mfma_f32_16x16x32_f16(a0, b, acc[0][nt], 0, 0, 0);
            acc[1][nt] = __builtin_amdgcn_mfma_f32_16x16x32_f16(a1, b, acc[1][nt], 0, 0, 0);
        }
    }

#pragma unroll
    for (int mt = 0; mt < 2; ++mt) {
#pragma unroll
        for (int nt = 0; nt < 4; ++nt) {
            int gc = colBase + nt * 16 + m;
            half_t* Y = (gc < C1) ? (Y1 + gc) : (Y2 + (gc - C1));
#pragma unroll
            for (int r = 0; r < 4; ++r) {
                int gr = rowBase + mt * 16 + quad * 4 + r;
                if (gr < Nr) Y[(size_t)gr * C1] = (half_t)acc[mt][nt][r];
            }
        }
    }
}

// ---------------- CSR construction ----------------
// Self-loops prefilled in scan_chunks; count_dst/fill_adj touch only E real edges.

__global__ void count_dst(const int* __restrict__ ei, int* __restrict__ counts, int E) {
    int e = blockIdx.x * blockDim.x + threadIdx.x;
    if (e >= E) return;
    atomicAdd(&counts[ei[E + e]], 1);
}

#define SCAN_CH 2048  // 256 threads x 8

__global__ void reduce_chunks(const int* __restrict__ counts, int* __restrict__ partial, int N) {
    __shared__ int sh[256];
    int t = threadIdx.x, base = blockIdx.x * SCAN_CH + t * 8;
    int s = 0;
    for (int j = 0; j < 8; ++j) if (base + j < N) s += counts[base + j] + 1;  // +1 self-loop
    sh[t] = s; __syncthreads();
    for (int off = 128; off >= 1; off >>= 1) {
        if (t < off) sh[t] += sh[t + off];
        __syncthreads();
    }
    if (t == 0) partial[blockIdx.x] = sh[0];
}

__global__ void scan_partials(int* __restrict__ partial, int nch) {
    if (threadIdx.x == 0 && blockIdx.x == 0) {
        int run = 0;
        for (int i = 0; i < nch; ++i) { int v = partial[i]; partial[i] = run; run += v; }
    }
}

// Writes offsets; seeds cursor past the self-loop; prefills the self-loop
// into adj; updates counts to true degree (incl. self-loop).
__global__ void scan_chunks(int* __restrict__ counts, const int* __restrict__ partial,
                            int* __restrict__ offsets, int* __restrict__ cursor,
                            int* __restrict__ adj, int N) {
    __shared__ int sh[256];
    int t = threadIdx.x, b = blockIdx.x, base = b * SCAN_CH + t * 8;
    int v[8], s = 0;
    for (int j = 0; j < 8; ++j) {
        v[j] = (base + j < N) ? (counts[base + j] + 1) : 0;
        s += v[j];
    }
    sh[t] = s; __syncthreads();
    for (int off = 1; off < 256; off <<= 1) {
        int x = (t >= off) ? sh[t - off] : 0;
        __syncthreads();
        sh[t] += x;
        __syncthreads();
    }
    int run = partial[b] + (t == 0 ? 0 : sh[t - 1]);
    for (int j = 0; j < 8; ++j) {
        if (base + j < N) {
            offsets[base + j] = run;
            adj[run] = base + j;       // self-loop first
            cursor[base + j] = run + 1;
            counts[base + j] = v[j];   // true degree (incl. self-loop)
        }
        run += v[j];
    }
}

// XCD-sliced adj scatter (verified R12: removed fill_adj's 53 MB write-back
// amplification). Block b handles dst slice b&7 (blockIdx%8 ~ XCD round-robin),
// so all stores to one adj region write-combine in one XCD's L2.
__global__ __launch_bounds__(256) void fill_adj_sliced(
        const int* __restrict__ ei, int* __restrict__ cursor,
        int* __restrict__ adj, int E, int sliceSz) {
    int slice = blockIdx.x & 7;
    int lo = slice * sliceSz, hi = lo + sliceSz;
    int nb = gridDim.x >> 3;          // blocks per slice
    int bi = blockIdx.x >> 3;
    int stride = nb * 256;
    for (int e = bi * 256 + threadIdx.x; e < E; e += stride) {
        int d = ei[E + e];
        if (d >= lo && d < hi) {
            int pos = atomicAdd(&cursor[d], 1);
            adj[pos] = ei[e];
        }
    }
}

// R14: sort each dst's adjacency list ascending by src id (one wave per dst,
// 64-lane odd-even transposition via shuffles). Order is a pure perf
// heuristic: sorted lists make concurrently-resident waves sweep src-space
// in a narrow band -> L2 hit rate up on the gat gathers (the saturated
// ~2.45 TB/s L2-miss path was the R13 bottleneck). deg>64 tail (doesn't
// occur for Poisson(17)): only first 64 sorted, multiset preserved.
__global__ __launch_bounds__(256) void sort_adj(
        const int* __restrict__ offsets, const int* __restrict__ counts,
        int* __restrict__ adj, int N) {
    int wave = threadIdx.x >> 6, lane = threadIdx.x & 63;
    int d = blockIdx.x * 4 + wave;
    if (d >= N) return;
    int off = offsets[d];
    int deg = counts[d];
    int m = (deg < 64) ? deg : 64;
    int v = (lane < m) ? adj[off + lane] : 0x7fffffff;
#pragma unroll 4
    for (int r = 0; r < 64; ++r) {
        int p;
        if ((r & 1) == 0) p = lane ^ 1;
        else p = (lane == 0 || lane == 63) ? lane : ((lane & 1) ? lane + 1 : lane - 1);
        int pv = __shfl(v, p);
        v = (lane < p) ? ((v < pv) ? v : pv) : ((lane > p) ? ((v > pv) ? v : pv) : v);
    }
    if (lane < m) adj[off + lane] = v;
}

// ---------------- fused GATv2 ----------------
// 16 lanes/dst (8 halfs each), 4 dsts/wave -> 12500 waves, unroll x4 with
// software-pipelined adj index prefetch. R14: lists are src-sorted for L2
// locality (see sort_adj).

__global__ __launch_bounds__(256) void gat16_h4(
        const half_t* __restrict__ xl, const half_t* __restrict__ xr,
        const half_t* __restrict__ atth, const int* __restrict__ offsets,
        const int* __restrict__ counts, const int* __restrict__ adj,
        const float* __restrict__ bias, half_t* __restrict__ out, int N) {
    int wave = threadIdx.x >> 6, lane = threadIdx.x & 63;
    int g = lane >> 4, t = lane & 15;
    int d = blockIdx.x * 16 + wave * 4 + g;
    int dc = (d < N) ? d : (N - 1);
    int off = offsets[dc];
    int deg = (d < N) ? counts[dc] : 0;
    int dmax = deg;
    dmax = max(dmax, __shfl_xor(dmax, 16));
    dmax = max(dmax, __shfl_xor(dmax, 32));

    h8 xr8 = *(const h8*)(xr + (size_t)dc * 128 + t * 8);
    H8u at8; at8.v = *(const h8*)(atth + t * 8);

    float acc[8];
#pragma unroll
    for (int j = 0; j < 8; ++j) acc[j] = 0.f;
    float lsum = 0.f;
    h8 c02;
#pragma unroll
    for (int j = 0; j < 8; ++j) c02[j] = (half_t)0.2f;

    bool v0 = 0 < deg, v1 = 1 < deg, v2 = 2 < deg, v3 = 3 < deg;
    int s0 = adj[off];
    int s1 = adj[off + (v1 ? 1 : 0)];
    int s2 = adj[off + (v2 ? 2 : 0)];
    int s3 = adj[off + (v3 ? 3 : 0)];

    for (int i = 0; i < dmax; i += 4) {
        H8u a0, a1, a2, a3;
        a0.v = *(const h8*)(xl + (size_t)s0 * 128 + t * 8);
        a1.v = *(const h8*)(xl + (size_t)s1 * 128 + t * 8);
        a2.v = *(const h8*)(xl + (size_t)s2 * 128 + t * 8);
        a3.v = *(const h8*)(xl + (size_t)s3 * 128 + t * 8);
        // prefetch next iteration's indices while the gathers are in flight
        int ni = i + 4;
        bool nv0 = ni < deg, nv1 = ni + 1 < deg, nv2 = ni + 2 < deg, nv3 = ni + 3 < deg;
        int n0 = adj[off + (nv0 ? ni : 0)];
        int n1 = adj[off + (nv1 ? ni + 1 : 0)];
        int n2 = adj[off + (nv2 ? ni + 2 : 0)];
        int n3 = adj[off + (nv3 ? ni + 3 : 0)];

        h8 e0 = a0.v + xr8, e1 = a1.v + xr8, e2 = a2.v + xr8, e3 = a3.v + xr8;
        H8u l0, l1, l2, l3;
        l0.v = hmax8(e0, e0 * c02);
        l1.v = hmax8(e1, e1 * c02);
        l2.v = hmax8(e2, e2 * c02);
        l3.v = hmax8(e3, e3 * c02);
        float p0 = 0.f, p1 = 0.f, p2 = 0.f, p3 = 0.f;
#pragma unroll
        for (int j = 0; j < 4; ++j) {
            p0 = dot2acc(l0.h2[j], at8.h2[j], p0);
            p1 = dot2acc(l1.h2[j], at8.h2[j], p1);
            p2 = dot2acc(l2.h2[j], at8.h2[j], p2);
            p3 = dot2acc(l3.h2[j], at8.h2[j], p3);
        }
        // head = t>>2; sum the 4 lanes (32 channels) of this head
        p0 += __shfl_xor(p0, 1); p1 += __shfl_xor(p1, 1);
        p2 += __shfl_xor(p2, 1); p3 += __shfl_xor(p3, 1);
        p0 += __shfl_xor(p0, 2); p1 += __shfl_xor(p1, 2);
        p2 += __shfl_xor(p2, 2); p3 += __shfl_xor(p3, 2);
        float w0 = v0 ? __expf(p0) : 0.f;
        float w1 = v1 ? __expf(p1) : 0.f;
        float w2 = v2 ? __expf(p2) : 0.f;
        float w3 = v3 ? __expf(p3) : 0.f;
        lsum += (w0 + w1) + (w2 + w3);
#pragma unroll
        for (int j = 0; j < 8; ++j)
            acc[j] += w0 * (float)a0.e[j] + w1 * (float)a1.e[j]
                    + w2 * (float)a2.e[j] + w3 * (float)a3.e[j];
        s0 = n0; s1 = n1; s2 = n2; s3 = n3;
        v0 = nv0; v1 = nv1; v2 = nv2; v3 = nv3;
    }

    if (d < N) {
        float inv = 1.f / lsum;
        H8u o;
#pragma unroll
        for (int j = 0; j < 8; ++j)
            o.e[j] = (half_t)fmaxf(acc[j] * inv + bias[t * 8 + j], 0.f);
        *(h8*)(out + (size_t)d * 128 + t * 8) = o.v;
    }
}

// H=1, 32 features. 16 lanes/dst as two 8-lane subgroups; subgroup `sub`
// processes edges i ≡ sub (mod 2) with 4 chains (i, i+2, i+4, i+6; step 8)
// + adj prefetch -> 8 edges in flight per dst. Partials combined across
// subgroups with one shfl_xor(8) at the end.
__global__ __launch_bounds__(256) void gat16_h1(
        const half_t* __restrict__ xl, const half_t* __restrict__ xr,
        const half_t* __restrict__ atth, const int* __restrict__ offsets,
        const int* __restrict__ counts, const int* __restrict__ adj,
        const float* __restrict__ bias, float* __restrict__ out, int N) {
    int wave = threadIdx.x >> 6, lane = threadIdx.x & 63;
    int g = lane >> 4, sub = (lane >> 3) & 1, t = lane & 7;
    int d = blockIdx.x * 16 + wave * 4 + g;
    int dc = (d < N) ? d : (N - 1);
    int off = offsets[dc];
    int deg = (d < N) ? counts[dc] : 0;
    int dmax = deg;
    dmax = max(dmax, __shfl_xor(dmax, 16));
    dmax = max(dmax, __shfl_xor(dmax, 32));

    h4v xr4 = *(const h4v*)(xr + (size_t)dc * 32 + t * 4);
    H4u at4; at4.v = *(const h4v*)(atth + t * 4);

    float acc[4] = {0.f, 0.f, 0.f, 0.f};
    float lsum = 0.f;
    h4v c02;
#pragma unroll
    for (int j = 0; j < 4; ++j) c02[j] = (half_t)0.2f;

    int i = sub;
    bool va = i < deg, vb = i + 2 < deg, vc = i + 4 < deg, vd = i + 6 < deg;
    int sa = adj[off + (va ? i : 0)];
    int sb = adj[off + (vb ? i + 2 : 0)];
    int sc = adj[off + (vc ? i + 4 : 0)];
    int sd = adj[off + (vd ? i + 6 : 0)];
    for (; i < dmax; i += 8) {
        H4u a, b, c, e;
        a.v = *(const h4v*)(xl + (size_t)sa * 32 + t * 4);
        b.v = *(const h4v*)(xl + (size_t)sb * 32 + t * 4);
        c.v = *(const h4v*)(xl + (size_t)sc * 32 + t * 4);
        e.v = *(const h4v*)(xl + (size_t)sd * 32 + t * 4);
        int ni = i + 8;
        bool nva = ni < deg, nvb = ni + 2 < deg, nvc = ni + 4 < deg, nvd = ni + 6 < deg;
        int na = adj[off + (nva ? ni : 0)];
        int nb = adj[off + (nvb ? ni + 2 : 0)];
        int nc = adj[off + (nvc ? ni + 4 : 0)];
        int nd = adj[off + (nvd ? ni + 6 : 0)];
        h4v ea = a.v + xr4, eb = b.v + xr4, ec = c.v + xr4, ed = e.v + xr4;
        H4u la, lb, lc, ld;
        la.v = hmax4(ea, ea * c02);
        lb.v = hmax4(eb, eb * c02);
        lc.v = hmax4(ec, ec * c02);
        ld.v = hmax4(ed, ed * c02);
        float pa = dot2acc(la.h2[0], at4.h2[0], 0.f);
        float pb = dot2acc(lb.h2[0], at4.h2[0], 0.f);
        float pc = dot2acc(lc.h2[0], at4.h2[0], 0.f);
        float pd = dot2acc(ld.h2[0], at4.h2[0], 0.f);
        pa = dot2acc(la.h2[1], at4.h2[1], pa);
        pb = dot2acc(lb.h2[1], at4.h2[1], pb);
        pc = dot2acc(lc.h2[1], at4.h2[1], pc);
        pd = dot2acc(ld.h2[1], at4.h2[1], pd);
        pa += __shfl_xor(pa, 1); pb += __shfl_xor(pb, 1);
        pc += __shfl_xor(pc, 1); pd += __shfl_xor(pd, 1);
        pa += __shfl_xor(pa, 2); pb += __shfl_xor(pb, 2);
        pc += __shfl_xor(pc, 2); pd += __shfl_xor(pd, 2);
        pa += __shfl_xor(pa, 4); pb += __shfl_xor(pb, 4);
        pc += __shfl_xor(pc, 4); pd += __shfl_xor(pd, 4);
        float wa = va ? __expf(pa) : 0.f;
        float wb = vb ? __expf(pb) : 0.f;
        float wc = vc ? __expf(pc) : 0.f;
        float wd = vd ? __expf(pd) : 0.f;
        lsum += (wa + wb) + (wc + wd);
#pragma unroll
        for (int j = 0; j < 4; ++j)
            acc[j] += wa * (float)a.e[j] + wb * (float)b.e[j]
                    + wc * (float)c.e[j] + wd * (float)e.e[j];
        sa = na; sb = nb; sc = nc; sd = nd;
        va = nva; vb = nvb; vc = nvc; vd = nvd;
    }

    // combine the two subgroups (differ only in lane bit 3)
    lsum += __shfl_xor(lsum, 8);
#pragma unroll
    for (int j = 0; j < 4; ++j) acc[j] += __shfl_xor(acc[j], 8);

    if (d < N && sub == 0) {
        float inv = 1.f / lsum;
        float4 o;
        o.x = fmaxf(acc[0] * inv + bias[t * 4 + 0], 0.f);
        o.y = fmaxf(acc[1] * inv + bias[t * 4 + 1], 0.f);
        o.z = fmaxf(acc[2] * inv + bias[t * 4 + 2], 0.f);
        o.w = fmaxf(acc[3] * inv + bias[t * 4 + 3], 0.f);
        *(float4*)(out + (size_t)d * 32 + t * 4) = o;
    }
}

// ---------------- map branch ----------------

__global__ void map_sum_kernel(const float* __restrict__ lane_x, const float* __restrict__ map_W,
                               const float* __restrict__ map_b, float* __restrict__ sums, int M) {
    __shared__ float s[32];
    if (threadIdx.x < 32) s[threadIdx.x] = 0.f;
    __syncthreads();
    int t = blockIdx.x * blockDim.x + threadIdx.x;
    int nth = gridDim.x * blockDim.x;
    int c = t & 31;
    float w0 = map_W[c], w1 = map_W[32 + c], bb = map_b[c];
    float acc = 0.f;
    for (int m = t >> 5; m < M; m += nth >> 5) {
        float v = lane_x[(long)m * 2] * w0 + lane_x[(long)m * 2 + 1] * w1 + bb;
        acc += fmaxf(v, 0.f);
    }
    atomicAdd(&s[c], acc);
    __syncthreads();
    if (threadIdx.x < 32) atomicAdd(&sums[threadIdx.x], s[threadIdx.x]);
}

// ---------------- fused head ----------------

__global__ void head_kernel(const float* __restrict__ gf, const int* __restrict__ focal_idx,
                            const float* __restrict__ map_sums, int M,
                            const float* __restrict__ centerline, int L,
                            const float* __restrict__ cl_W, const float* __restrict__ cl_b,
                            const float* __restrict__ fc1_W, const float* __restrict__ fc1_b,
                            const float* __restrict__ fc2_W, const float* __restrict__ fc2_b,
                            const float* __restrict__ fco_W, const float* __restrict__ fco_b,
                            float* __restrict__ out) {
    int f = blockIdx.x;
    int lane = threadIdx.x;
    __shared__ float s_comb[96];
    __shared__ float s_h1[32];
    __shared__ float s_h2[16];
    __shared__ float s_cl[2];

    float c0 = 0.f, c1 = 0.f;
    if (lane < L) {
        c0 = centerline[((long)f * L + lane) * 2 + 0];
        c1 = centerline[((long)f * L + lane) * 2 + 1];
    }
    for (int off = 32; off >= 1; off >>= 1) {
        c0 += __shfl_down(c0, off);
        c1 += __shfl_down(c1, off);
    }
    if (lane == 0) { s_cl[0] = c0 / (float)L; s_cl[1] = c1 / (float)L; }
    __syncthreads();

    int fi = focal_idx[f];
    if (lane < 32) {
        s_comb[lane] = gf[(long)fi * 32 + lane];
        s_comb[32 + lane] = map_sums[lane] / (float)M;
        s_comb[64 + lane] = s_cl[0] * cl_W[lane] + s_cl[1] * cl_W[32 + lane] + cl_b[lane];
    }
    __syncthreads();

    if (lane < 32) {
        float acc = fc1_b[lane];
        for (int k = 0; k < 96; ++k) acc += s_comb[k] * fc1_W[k * 32 + lane];
        s_h1[lane] = fmaxf(acc, 0.f);
    }
    __syncthreads();

    if (lane < 16) {
        float acc = fc2_b[lane];
        for (int k = 0; k < 32; ++k) acc += s_h1[k] * fc2_W[k * 16 + lane];
        s_h2[lane] = fmaxf(acc, 0.f);
    }
    __syncthreads();

    if (lane < 60) {
        float acc = fco_b[lane];
        for (int k = 0; k < 16; ++k) acc += s_h2[k] * fco_W[k * 60 + lane];
        out[(long)f * 60 + lane] = acc;
    }
}

// ---------------- launch ----------------

extern "C" void kernel_launch(void* const* d_in, const int* in_sizes, int n_in,
                              void* d_out, int out_size, void* d_ws, size_t ws_size,
                              hipStream_t stream) {
    const float* x          = (const float*)d_in[0];
    const float* lane_x     = (const float*)d_in[1];
    const float* centerline = (const float*)d_in[2];
    const int*   ei         = (const int*)d_in[3];
    const int*   focal_idx  = (const int*)d_in[4];
    const float* emb_W = (const float*)d_in[5];
    const float* emb_b = (const float*)d_in[6];
    const float* c1_Wl = (const float*)d_in[7];
    const float* c1_Wr = (const float*)d_in[8];
    const float* c1_att = (const float*)d_in[9];
    const float* c1_b  = (const float*)d_in[10];
    const float* c2_Wl = (const float*)d_in[11];
    const float* c2_Wr = (const float*)d_in[12];
    const float* c2_att = (const float*)d_in[13];
    const float* c2_b  = (const float*)d_in[14];
    const float* map_W = (const float*)d_in[15];
    const float* map_b = (const float*)d_in[16];
    const float* gg_Wl = (const float*)d_in[17];
    const float* gg_Wr = (const float*)d_in[18];
    const float* gg_att = (const float*)d_in[19];
    const float* gg_b  = (const float*)d_in[20];
    const float* cl_W  = (const float*)d_in[21];
    const float* cl_b  = (const float*)d_in[22];
    const float* fc1_W = (const float*)d_in[23];
    const float* fc1_b = (const float*)d_in[24];
    const float* fc2_W = (const float*)d_in[25];
    const float* fc2_b = (const float*)d_in[26];
    const float* fco_W = (const float*)d_in[27];
    const float* fco_b = (const float*)d_in[28];

    const int N = in_sizes[0] / 60;
    const int M = in_sizes[1] / 2;
    const int F = in_sizes[4];
    const int L = in_sizes[2] / (F * 2);
    const int E = in_sizes[3] / 2;
    const int Etot = E + N;

    // Workspace layout:
    half_t* Xl_h = (half_t*)d_ws;                    // N*128
    half_t* Xr_h = Xl_h + (size_t)N * 128;           // N*128
    half_t* H0_h = Xr_h + (size_t)N * 128;           // N*32
    half_t* H1_h = H0_h + (size_t)N * 32;            // N*128
    half_t* AF_h = H1_h + (size_t)N * 128;           // N*128
    float*  GF_f = (float*)(AF_h + (size_t)N * 128); // N*32 f32
    half_t* Wt   = (half_t*)(GF_f + (size_t)N * 32); // 49440 halfs
    int* counts  = (int*)(Wt + 49440);               // N
    int* offsets = counts + N;                        // N
    int* cursor  = offsets + N;                       // N
    int* adj     = cursor + N;                        // Etot
    float* MAPS  = (float*)(adj + Etot);              // 32
    int* partial = (int*)(MAPS + 32);                 // nch

    half_t* c1Wlt = Wt + 0;
    half_t* c1Wrt = Wt + 4096;
    half_t* c2Wlt = Wt + 8192;
    half_t* c2Wrt = Wt + 24576;
    half_t* ggWlt = Wt + 40960;
    half_t* ggWrt = Wt + 45056;
    half_t* att1h = Wt + 49152;
    half_t* att2h = Wt + 49280;
    half_t* attgh = Wt + 49408;

    const int BS = 256;
    const int nch = cdiv(N, SCAN_CH);
    const int rowBlocks = cdiv(N, 128);
    const int sliceSz = cdiv(N, 8);

    // ---- CSR build (self-loops prefilled in scan_chunks; XCD-sliced scatter) ----
    hipMemsetAsync(counts, 0, (size_t)N * sizeof(int), stream);
    count_dst<<<cdiv(E, BS), BS, 0, stream>>>(ei, counts, E);
    reduce_chunks<<<nch, 256, 0, stream>>>(counts, partial, N);
    scan_partials<<<1, 64, 0, stream>>>(partial, nch);
    scan_chunks<<<nch, 256, 0, stream>>>(counts, partial, offsets, cursor, adj, N);
    fill_adj_sliced<<<8 * 104, 256, 0, stream>>>(ei, cursor, adj, E, sliceSz);
    sort_adj<<<cdiv(N, 4), 256, 0, stream>>>(offsets, counts, adj, N);

    // ---- weights + att -> f16 ----
    wtrans<<<cdiv(49440, BS), BS, 0, stream>>>(c1_Wl, c1_Wr, c2_Wl, c2_Wr, gg_Wl, gg_Wr,
                                               c1_att, c2_att, gg_att, Wt);

    // ---- h0 = relu(x @ emb_W + emb_b) -> H0_h ----
    gemm_t_h<15, 8, 4><<<cdiv((long)(N / 4) * 8, BS), BS, 0, stream>>>(x, emb_W, emb_b, H0_h, N, 1);

    // ---- layer 1 (H=4) ----
    mfma_dual<32, 128><<<rowBlocks * 4, 256, 0, stream>>>(H0_h, c1Wlt, c1Wrt, Xl_h, Xr_h, N);
    gat16_h4<<<cdiv(N, 16), 256, 0, stream>>>(Xl_h, Xr_h, att1h, offsets, counts, adj, c1_b, H1_h, N);

    // ---- layer 2 (H=4) ----
    mfma_dual<128, 128><<<rowBlocks * 4, 256, 0, stream>>>(H1_h, c2Wlt, c2Wrt, Xl_h, Xr_h, N);
    gat16_h4<<<cdiv(N, 16), 256, 0, stream>>>(Xl_h, Xr_h, att2h, offsets, counts, adj, c2_b, AF_h, N);

    // ---- global graph (H=1) ----
    mfma_dual<128, 32><<<rowBlocks * 1, 256, 0, stream>>>(AF_h, ggWlt, ggWrt, Xl_h, Xr_h, N);
    gat16_h1<<<cdiv(N, 16), 256, 0, stream>>>(Xl_h, Xr_h, attgh, offsets, counts, adj, gg_b, GF_f, N);

    // ---- map branch ----
    hipMemsetAsync(MAPS, 0, 32 * sizeof(float), stream);
    map_sum_kernel<<<64, BS, 0, stream>>>(lane_x, map_W, map_b, MAPS, M);

    // ---- fused head ----
    head_kernel<<<F, 64, 0, stream>>>(GF_f, focal_idx, MAPS, M, centerline, L,
                                      cl_W, cl_b, fc1_W, fc1_b, fc2_W, fc2_b,
                                      fco_W, fco_b, (float*)d_out);
}

// Round 3
// 391.517 us; speedup vs baseline: 1.0694x; 1.0694x over previous
//
#include <hip/hip_runtime.h>
#include <hip/hip_bf16.h>
#include <hip/hip_fp16.h>

typedef _Float16 half_t;
typedef _Float16 h8 __attribute__((ext_vector_type(8)));
typedef _Float16 h4v __attribute__((ext_vector_type(4)));
typedef _Float16 h2v __attribute__((ext_vector_type(2)));
typedef float f4v __attribute__((ext_vector_type(4)));

union H8u { h8 v; h2v h2[4]; _Float16 e[8]; };
union H4u { h4v v; h2v h2[2]; _Float16 e[4]; };

static inline int cdiv(long a, long b) { return (int)((a + b - 1) / b); }

__device__ __forceinline__ void fma4(float4& a, float s, const float4& w) {
    a.x += s * w.x; a.y += s * w.y; a.z += s * w.z; a.w += s * w.w;
}

__device__ __forceinline__ h8 hmax8(h8 a, h8 b) {
#if __has_builtin(__builtin_elementwise_max)
    return __builtin_elementwise_max(a, b);
#else
    h8 r;
#pragma unroll
    for (int j = 0; j < 8; ++j) r[j] = (a[j] > b[j]) ? a[j] : b[j];
    return r;
#endif
}
__device__ __forceinline__ h4v hmax4(h4v a, h4v b) {
#if __has_builtin(__builtin_elementwise_max)
    return __builtin_elementwise_max(a, b);
#else
    h4v r;
#pragma unroll
    for (int j = 0; j < 4; ++j) r[j] = (a[j] > b[j]) ? a[j] : b[j];
    return r;
#endif
}

__device__ __forceinline__ float dot2acc(h2v a, h2v b, float c) {
#if __has_builtin(__builtin_amdgcn_fdot2)
    return __builtin_amdgcn_fdot2(a, b, c, false);
#else
    return c + (float)a.x * (float)b.x + (float)a.y * (float)b.y;
#endif
}

// ---------------- emb GEMM (fp32 compute, fp16 out) ----------------

template <int K4, int C4, int R>
__global__ __launch_bounds__(256) void gemm_t_h(
        const float* __restrict__ X, const float* __restrict__ W,
        const float* __restrict__ bias, half_t* __restrict__ Y,
        int Nr, int relu) {
    int idx = blockIdx.x * blockDim.x + threadIdx.x;
    int total = (Nr / R) * C4;
    if (idx >= total) return;
    int c4 = idx % C4;
    int n0 = (idx / C4) * R;
    const float4* __restrict__ Wv = (const float4*)W;
    const float4* __restrict__ Xv = (const float4*)X;
    float4 acc[R];
    float4 binit = bias ? ((const float4*)bias)[c4] : make_float4(0.f, 0.f, 0.f, 0.f);
#pragma unroll
    for (int r = 0; r < R; ++r) acc[r] = binit;
#pragma unroll 4
    for (int k4 = 0; k4 < K4; ++k4) {
        float4 w0 = Wv[(size_t)(4 * k4 + 0) * C4 + c4];
        float4 w1 = Wv[(size_t)(4 * k4 + 1) * C4 + c4];
        float4 w2 = Wv[(size_t)(4 * k4 + 2) * C4 + c4];
        float4 w3 = Wv[(size_t)(4 * k4 + 3) * C4 + c4];
#pragma unroll
        for (int r = 0; r < R; ++r) {
            float4 xv = Xv[(size_t)(n0 + r) * K4 + k4];
            fma4(acc[r], xv.x, w0); fma4(acc[r], xv.y, w1);
            fma4(acc[r], xv.z, w2); fma4(acc[r], xv.w, w3);
        }
    }
#pragma unroll
    for (int r = 0; r < R; ++r) {
        float4 o = acc[r];
        if (relu) {
            o.x = fmaxf(o.x, 0.f); o.y = fmaxf(o.y, 0.f);
            o.z = fmaxf(o.z, 0.f); o.w = fmaxf(o.w, 0.f);
        }
        h4v oh; oh.x = (half_t)o.x; oh.y = (half_t)o.y; oh.z = (half_t)o.z; oh.w = (half_t)o.w;
        ((h4v*)Y)[(size_t)(n0 + r) * C4 + c4] = oh;
    }
}

// ---------------- weight transpose+convert + att convert ----------------

__global__ void wtrans(const float* __restrict__ c1l, const float* __restrict__ c1r,
                       const float* __restrict__ c2l, const float* __restrict__ c2r,
                       const float* __restrict__ ggl, const float* __restrict__ ggr,
                       const float* __restrict__ at1, const float* __restrict__ at2,
                       const float* __restrict__ atg, half_t* __restrict__ dst) {
    int idx = blockIdx.x * blockDim.x + threadIdx.x;
    if (idx >= 49440) return;
    if (idx >= 49152) {
        int j = idx - 49152;
        float v = (j < 128) ? at1[j] : (j < 256) ? at2[j - 128] : atg[j - 256];
        dst[idx] = (half_t)v;
        return;
    }
    const float* src; int K, loc;
    if (idx < 8192) {
        K = 32;
        if (idx < 4096) { src = c1l; loc = idx; } else { src = c1r; loc = idx - 4096; }
        int k = loc % K, c = loc / K;
        dst[idx] = (half_t)src[k * 128 + c];
    } else if (idx < 40960) {
        K = 128;
        if (idx < 24576) { src = c2l; loc = idx - 8192; } else { src = c2r; loc = idx - 24576; }
        int k = loc % K, c = loc / K;
        dst[idx] = (half_t)src[k * 128 + c];
    } else {
        K = 128;
        if (idx < 45056) { src = ggl; loc = idx - 40960; } else { src = ggr; loc = idx - 45056; }
        int k = loc % K, c = loc / K;
        dst[idx] = (half_t)src[k * 32 + c];
    }
}

// ---------------- MFMA dual GEMM ----------------

template <int K, int C1>
__global__ __launch_bounds__(256) void mfma_dual(
        const half_t* __restrict__ Xh,
        const half_t* __restrict__ W1t, const half_t* __restrict__ W2t,
        half_t* __restrict__ Y1, half_t* __restrict__ Y2, int Nr) {
    constexpr int KT = K / 32;
    constexpr int NBC = (2 * C1) / 64;
    int wave = threadIdx.x >> 6, lane = threadIdx.x & 63;
    int bCol = blockIdx.x % NBC;
    int bRow = blockIdx.x / NBC;
    int rowBase = bRow * 128 + wave * 32;
    int colBase = bCol * 64;
    int m = lane & 15, quad = lane >> 4;

    f4v acc[2][4] = {};

    const half_t* bptr[4];
#pragma unroll
    for (int nt = 0; nt < 4; ++nt) {
        int gc = colBase + nt * 16 + m;
        bptr[nt] = (gc < C1) ? (W1t + (size_t)gc * K) : (W2t + (size_t)(gc - C1) * K);
    }
    int r0 = rowBase + m, r1 = rowBase + 16 + m;
    int r0c = (r0 < Nr) ? r0 : (Nr - 1);
    int r1c = (r1 < Nr) ? r1 : (Nr - 1);
    const half_t* a0p = Xh + (size_t)r0c * K + quad * 8;
    const half_t* a1p = Xh + (size_t)r1c * K + quad * 8;

#pragma unroll
    for (int kk = 0; kk < KT; ++kk) {
        h8 a0 = *(const h8*)(a0p + kk * 32);
        h8 a1 = *(const h8*)(a1p + kk * 32);
#pragma unroll
        for (int nt = 0; nt < 4; ++nt) {
            h8 b = *(const h8*)(bptr[nt] + kk * 32 + quad * 8);
            acc[0][nt] = __builtin_amdgcn_mfma_f32_16x16x32_f16(a0, b, acc[0][nt], 0, 0, 0);
            acc[1][nt] = __builtin_amdgcn_mfma_f32_16x16x32_f16(a1, b, acc[1][nt], 0, 0, 0);
        }
    }

#pragma unroll
    for (int mt = 0; mt < 2; ++mt) {
#pragma unroll
        for (int nt = 0; nt < 4; ++nt) {
            int gc = colBase + nt * 16 + m;
            half_t* Y = (gc < C1) ? (Y1 + gc) : (Y2 + (gc - C1));
#pragma unroll
            for (int r = 0; r < 4; ++r) {
                int gr = rowBase + mt * 16 + quad * 4 + r;
                if (gr < Nr) Y[(size_t)gr * C1] = (half_t)acc[mt][nt][r];
            }
        }
    }
}

// ---------------- CSR construction, src-bucketed (R15) ----------------
// counts8[d*8 + (src>>13)]: 8 src-buckets of 8192 rows (2 MB xl window,
// L2-sized). The scatter then lands each dst list grouped by ascending src
// bucket -> same coarse gather locality the R14 sort bought (+11.6 us) at
// ~zero cost (sort_adj was 47 us of shuffle VALU -> removed). Self-loops are
// ordinary edges in the unified count/fill stream over Etot = E + N.

#define NBKT 8
#define BSH 13  // bucket = src >> 13 (8192-row buckets)

__global__ void count_dst8(const int* __restrict__ ei, int* __restrict__ counts8,
                           int E, int N) {
    int e = blockIdx.x * blockDim.x + threadIdx.x;
    if (e >= E + N) return;
    int d, s;
    if (e < E) { d = ei[E + e]; s = ei[e]; }
    else { d = e - E; s = d; }
    atomicAdd(&counts8[(size_t)d * NBKT + (s >> BSH)], 1);
}

#define SCAN_CH 2048  // 256 threads x 8

__global__ void reduce_chunks(const int* __restrict__ counts8, int* __restrict__ partial, int n8) {
    __shared__ int sh[256];
    int t = threadIdx.x, base = blockIdx.x * SCAN_CH + t * 8;
    int s = 0;
    for (int j = 0; j < 8; ++j) if (base + j < n8) s += counts8[base + j];
    sh[t] = s; __syncthreads();
    for (int off = 128; off >= 1; off >>= 1) {
        if (t < off) sh[t] += sh[t + off];
        __syncthreads();
    }
    if (t == 0) partial[blockIdx.x] = sh[0];
}

__global__ void scan_partials(int* __restrict__ partial, int nch) {
    if (threadIdx.x == 0 && blockIdx.x == 0) {
        int run = 0;
        for (int i = 0; i < nch; ++i) { int v = partial[i]; partial[i] = run; run += v; }
    }
}

__global__ void scan_chunks(const int* __restrict__ counts8, const int* __restrict__ partial,
                            int* __restrict__ offsets8, int* __restrict__ cursor8, int n8) {
    __shared__ int sh[256];
    int t = threadIdx.x, b = blockIdx.x, base = b * SCAN_CH + t * 8;
    int v[8], s = 0;
    for (int j = 0; j < 8; ++j) {
        v[j] = (base + j < n8) ? counts8[base + j] : 0;
        s += v[j];
    }
    sh[t] = s; __syncthreads();
    for (int off = 1; off < 256; off <<= 1) {
        int x = (t >= off) ? sh[t - off] : 0;
        __syncthreads();
        sh[t] += x;
        __syncthreads();
    }
    int run = partial[b] + (t == 0 ? 0 : sh[t - 1]);
    for (int j = 0; j < 8; ++j) {
        if (base + j < n8) {
            offsets8[base + j] = run;
            cursor8[base + j] = run;
        }
        run += v[j];
    }
}

// XCD-sliced adj scatter; block b handles dst slice b&7 so stores to one adj
// region write-combine in one XCD's L2. Covers Etot edges (incl. self-loops).
__global__ __launch_bounds__(256) void fill_adj_sliced(
        const int* __restrict__ ei, int* __restrict__ cursor8,
        int* __restrict__ adj, int E, int N, int sliceSz) {
    int slice = blockIdx.x & 7;
    int lo = slice * sliceSz, hi = lo + sliceSz;
    int nb = gridDim.x >> 3;          // blocks per slice
    int bi = blockIdx.x >> 3;
    int stride = nb * 256;
    int Etot = E + N;
    for (int e = bi * 256 + threadIdx.x; e < Etot; e += stride) {
        int d, s;
        if (e < E) { d = ei[E + e]; s = ei[e]; }
        else { d = e - E; s = d; }
        if (d >= lo && d < hi) {
            int pos = atomicAdd(&cursor8[(size_t)d * NBKT + (s >> BSH)], 1);
            adj[pos] = s;
        }
    }
}

// ---------------- fused GATv2 ----------------
// 16 lanes/dst (8 halfs each), 4 dsts/wave -> 12500 waves, unroll x4 with
// software-pipelined adj index prefetch. Lists are src-bucket-grouped by
// construction (see CSR above). off/deg from offsets8 (stride 8 per dst).

__global__ __launch_bounds__(256) void gat16_h4(
        const half_t* __restrict__ xl, const half_t* __restrict__ xr,
        const half_t* __restrict__ atth, const int* __restrict__ offsets8,
        const int* __restrict__ adj,
        const float* __restrict__ bias, half_t* __restrict__ out, int N, int Etot) {
    int wave = threadIdx.x >> 6, lane = threadIdx.x & 63;
    int g = lane >> 4, t = lane & 15;
    int d = blockIdx.x * 16 + wave * 4 + g;
    int dc = (d < N) ? d : (N - 1);
    int off = offsets8[(size_t)dc * NBKT];
    int nxt = (dc < N - 1) ? offsets8[(size_t)(dc + 1) * NBKT] : Etot;
    int deg = (d < N) ? (nxt - off) : 0;
    int dmax = deg;
    dmax = max(dmax, __shfl_xor(dmax, 16));
    dmax = max(dmax, __shfl_xor(dmax, 32));

    h8 xr8 = *(const h8*)(xr + (size_t)dc * 128 + t * 8);
    H8u at8; at8.v = *(const h8*)(atth + t * 8);

    float acc[8];
#pragma unroll
    for (int j = 0; j < 8; ++j) acc[j] = 0.f;
    float lsum = 0.f;
    h8 c02;
#pragma unroll
    for (int j = 0; j < 8; ++j) c02[j] = (half_t)0.2f;

    bool v0 = 0 < deg, v1 = 1 < deg, v2 = 2 < deg, v3 = 3 < deg;
    int s0 = adj[off];
    int s1 = adj[off + (v1 ? 1 : 0)];
    int s2 = adj[off + (v2 ? 2 : 0)];
    int s3 = adj[off + (v3 ? 3 : 0)];

    for (int i = 0; i < dmax; i += 4) {
        H8u a0, a1, a2, a3;
        a0.v = *(const h8*)(xl + (size_t)s0 * 128 + t * 8);
        a1.v = *(const h8*)(xl + (size_t)s1 * 128 + t * 8);
        a2.v = *(const h8*)(xl + (size_t)s2 * 128 + t * 8);
        a3.v = *(const h8*)(xl + (size_t)s3 * 128 + t * 8);
        // prefetch next iteration's indices while the gathers are in flight
        int ni = i + 4;
        bool nv0 = ni < deg, nv1 = ni + 1 < deg, nv2 = ni + 2 < deg, nv3 = ni + 3 < deg;
        int n0 = adj[off + (nv0 ? ni : 0)];
        int n1 = adj[off + (nv1 ? ni + 1 : 0)];
        int n2 = adj[off + (nv2 ? ni + 2 : 0)];
        int n3 = adj[off + (nv3 ? ni + 3 : 0)];

        h8 e0 = a0.v + xr8, e1 = a1.v + xr8, e2 = a2.v + xr8, e3 = a3.v + xr8;
        H8u l0, l1, l2, l3;
        l0.v = hmax8(e0, e0 * c02);
        l1.v = hmax8(e1, e1 * c02);
        l2.v = hmax8(e2, e2 * c02);
        l3.v = hmax8(e3, e3 * c02);
        float p0 = 0.f, p1 = 0.f, p2 = 0.f, p3 = 0.f;
#pragma unroll
        for (int j = 0; j < 4; ++j) {
            p0 = dot2acc(l0.h2[j], at8.h2[j], p0);
            p1 = dot2acc(l1.h2[j], at8.h2[j], p1);
            p2 = dot2acc(l2.h2[j], at8.h2[j], p2);
            p3 = dot2acc(l3.h2[j], at8.h2[j], p3);
        }
        // head = t>>2; sum the 4 lanes (32 channels) of this head
        p0 += __shfl_xor(p0, 1); p1 += __shfl_xor(p1, 1);
        p2 += __shfl_xor(p2, 1); p3 += __shfl_xor(p3, 1);
        p0 += __shfl_xor(p0, 2); p1 += __shfl_xor(p1, 2);
        p2 += __shfl_xor(p2, 2); p3 += __shfl_xor(p3, 2);
        float w0 = v0 ? __expf(p0) : 0.f;
        float w1 = v1 ? __expf(p1) : 0.f;
        float w2 = v2 ? __expf(p2) : 0.f;
        float w3 = v3 ? __expf(p3) : 0.f;
        lsum += (w0 + w1) + (w2 + w3);
#pragma unroll
        for (int j = 0; j < 8; ++j)
            acc[j] += w0 * (float)a0.e[j] + w1 * (float)a1.e[j]
                    + w2 * (float)a2.e[j] + w3 * (float)a3.e[j];
        s0 = n0; s1 = n1; s2 = n2; s3 = n3;
        v0 = nv0; v1 = nv1; v2 = nv2; v3 = nv3;
    }

    if (d < N) {
        float inv = 1.f / lsum;
        H8u o;
#pragma unroll
        for (int j = 0; j < 8; ++j)
            o.e[j] = (half_t)fmaxf(acc[j] * inv + bias[t * 8 + j], 0.f);
        *(h8*)(out + (size_t)d * 128 + t * 8) = o.v;
    }
}

// H=1, 32 features. 16 lanes/dst as two 8-lane subgroups; subgroup `sub`
// processes edges i ≡ sub (mod 2) with 4 chains + adj prefetch -> 8 edges in
// flight per dst. Partials combined across subgroups with shfl_xor(8).
__global__ __launch_bounds__(256) void gat16_h1(
        const half_t* __restrict__ xl, const half_t* __restrict__ xr,
        const half_t* __restrict__ atth, const int* __restrict__ offsets8,
        const int* __restrict__ adj,
        const float* __restrict__ bias, float* __restrict__ out, int N, int Etot) {
    int wave = threadIdx.x >> 6, lane = threadIdx.x & 63;
    int g = lane >> 4, sub = (lane >> 3) & 1, t = lane & 7;
    int d = blockIdx.x * 16 + wave * 4 + g;
    int dc = (d < N) ? d : (N - 1);
    int off = offsets8[(size_t)dc * NBKT];
    int nxt = (dc < N - 1) ? offsets8[(size_t)(dc + 1) * NBKT] : Etot;
    int deg = (d < N) ? (nxt - off) : 0;
    int dmax = deg;
    dmax = max(dmax, __shfl_xor(dmax, 16));
    dmax = max(dmax, __shfl_xor(dmax, 32));

    h4v xr4 = *(const h4v*)(xr + (size_t)dc * 32 + t * 4);
    H4u at4; at4.v = *(const h4v*)(atth + t * 4);

    float acc[4] = {0.f, 0.f, 0.f, 0.f};
    float lsum = 0.f;
    h4v c02;
#pragma unroll
    for (int j = 0; j < 4; ++j) c02[j] = (half_t)0.2f;

    int i = sub;
    bool va = i < deg, vb = i + 2 < deg, vc = i + 4 < deg, vd = i + 6 < deg;
    int sa = adj[off + (va ? i : 0)];
    int sb = adj[off + (vb ? i + 2 : 0)];
    int sc = adj[off + (vc ? i + 4 : 0)];
    int sd = adj[off + (vd ? i + 6 : 0)];
    for (; i < dmax; i += 8) {
        H4u a, b, c, e;
        a.v = *(const h4v*)(xl + (size_t)sa * 32 + t * 4);
        b.v = *(const h4v*)(xl + (size_t)sb * 32 + t * 4);
        c.v = *(const h4v*)(xl + (size_t)sc * 32 + t * 4);
        e.v = *(const h4v*)(xl + (size_t)sd * 32 + t * 4);
        int ni = i + 8;
        bool nva = ni < deg, nvb = ni + 2 < deg, nvc = ni + 4 < deg, nvd = ni + 6 < deg;
        int na = adj[off + (nva ? ni : 0)];
        int nb = adj[off + (nvb ? ni + 2 : 0)];
        int nc = adj[off + (nvc ? ni + 4 : 0)];
        int nd = adj[off + (nvd ? ni + 6 : 0)];
        h4v ea = a.v + xr4, eb = b.v + xr4, ec = c.v + xr4, ed = e.v + xr4;
        H4u la, lb, lc, ld;
        la.v = hmax4(ea, ea * c02);
        lb.v = hmax4(eb, eb * c02);
        lc.v = hmax4(ec, ec * c02);
        ld.v = hmax4(ed, ed * c02);
        float pa = dot2acc(la.h2[0], at4.h2[0], 0.f);
        float pb = dot2acc(lb.h2[0], at4.h2[0], 0.f);
        float pc = dot2acc(lc.h2[0], at4.h2[0], 0.f);
        float pd = dot2acc(ld.h2[0], at4.h2[0], 0.f);
        pa = dot2acc(la.h2[1], at4.h2[1], pa);
        pb = dot2acc(lb.h2[1], at4.h2[1], pb);
        pc = dot2acc(lc.h2[1], at4.h2[1], pc);
        pd = dot2acc(ld.h2[1], at4.h2[1], pd);
        pa += __shfl_xor(pa, 1); pb += __shfl_xor(pb, 1);
        pc += __shfl_xor(pc, 1); pd += __shfl_xor(pd, 1);
        pa += __shfl_xor(pa, 2); pb += __shfl_xor(pb, 2);
        pc += __shfl_xor(pc, 2); pd += __shfl_xor(pd, 2);
        pa += __shfl_xor(pa, 4); pb += __shfl_xor(pb, 4);
        pc += __shfl_xor(pc, 4); pd += __shfl_xor(pd, 4);
        float wa = va ? __expf(pa) : 0.f;
        float wb = vb ? __expf(pb) : 0.f;
        float wc = vc ? __expf(pc) : 0.f;
        float wd = vd ? __expf(pd) : 0.f;
        lsum += (wa + wb) + (wc + wd);
#pragma unroll
        for (int j = 0; j < 4; ++j)
            acc[j] += wa * (float)a.e[j] + wb * (float)b.e[j]
                    + wc * (float)c.e[j] + wd * (float)e.e[j];
        sa = na; sb = nb; sc = nc; sd = nd;
        va = nva; vb = nvb; vc = nvc; vd = nvd;
    }

    // combine the two subgroups (differ only in lane bit 3)
    lsum += __shfl_xor(lsum, 8);
#pragma unroll
    for (int j = 0; j < 4; ++j) acc[j] += __shfl_xor(acc[j], 8);

    if (d < N && sub == 0) {
        float inv = 1.f / lsum;
        float4 o;
        o.x = fmaxf(acc[0] * inv + bias[t * 4 + 0], 0.f);
        o.y = fmaxf(acc[1] * inv + bias[t * 4 + 1], 0.f);
        o.z = fmaxf(acc[2] * inv + bias[t * 4 + 2], 0.f);
        o.w = fmaxf(acc[3] * inv + bias[t * 4 + 3], 0.f);
        *(float4*)(out + (size_t)d * 32 + t * 4) = o;
    }
}

// ---------------- map branch ----------------

__global__ void map_sum_kernel(const float* __restrict__ lane_x, const float* __restrict__ map_W,
                               const float* __restrict__ map_b, float* __restrict__ sums, int M) {
    __shared__ float s[32];
    if (threadIdx.x < 32) s[threadIdx.x] = 0.f;
    __syncthreads();
    int t = blockIdx.x * blockDim.x + threadIdx.x;
    int nth = gridDim.x * blockDim.x;
    int c = t & 31;
    float w0 = map_W[c], w1 = map_W[32 + c], bb = map_b[c];
    float acc = 0.f;
    for (int m = t >> 5; m < M; m += nth >> 5) {
        float v = lane_x[(long)m * 2] * w0 + lane_x[(long)m * 2 + 1] * w1 + bb;
        acc += fmaxf(v, 0.f);
    }
    atomicAdd(&s[c], acc);
    __syncthreads();
    if (threadIdx.x < 32) atomicAdd(&sums[threadIdx.x], s[threadIdx.x]);
}

// ---------------- fused head ----------------

__global__ void head_kernel(const float* __restrict__ gf, const int* __restrict__ focal_idx,
                            const float* __restrict__ map_sums, int M,
                            const float* __restrict__ centerline, int L,
                            const float* __restrict__ cl_W, const float* __restrict__ cl_b,
                            const float* __restrict__ fc1_W, const float* __restrict__ fc1_b,
                            const float* __restrict__ fc2_W, const float* __restrict__ fc2_b,
                            const float* __restrict__ fco_W, const float* __restrict__ fco_b,
                            float* __restrict__ out) {
    int f = blockIdx.x;
    int lane = threadIdx.x;
    __shared__ float s_comb[96];
    __shared__ float s_h1[32];
    __shared__ float s_h2[16];
    __shared__ float s_cl[2];

    float c0 = 0.f, c1 = 0.f;
    if (lane < L) {
        c0 = centerline[((long)f * L + lane) * 2 + 0];
        c1 = centerline[((long)f * L + lane) * 2 + 1];
    }
    for (int off = 32; off >= 1; off >>= 1) {
        c0 += __shfl_down(c0, off);
        c1 += __shfl_down(c1, off);
    }
    if (lane == 0) { s_cl[0] = c0 / (float)L; s_cl[1] = c1 / (float)L; }
    __syncthreads();

    int fi = focal_idx[f];
    if (lane < 32) {
        s_comb[lane] = gf[(long)fi * 32 + lane];
        s_comb[32 + lane] = map_sums[lane] / (float)M;
        s_comb[64 + lane] = s_cl[0] * cl_W[lane] + s_cl[1] * cl_W[32 + lane] + cl_b[lane];
    }
    __syncthreads();

    if (lane < 32) {
        float acc = fc1_b[lane];
        for (int k = 0; k < 96; ++k) acc += s_comb[k] * fc1_W[k * 32 + lane];
        s_h1[lane] = fmaxf(acc, 0.f);
    }
    __syncthreads();

    if (lane < 16) {
        float acc = fc2_b[lane];
        for (int k = 0; k < 32; ++k) acc += s_h1[k] * fc2_W[k * 16 + lane];
        s_h2[lane] = fmaxf(acc, 0.f);
    }
    __syncthreads();

    if (lane < 60) {
        float acc = fco_b[lane];
        for (int k = 0; k < 16; ++k) acc += s_h2[k] * fco_W[k * 60 + lane];
        out[(long)f * 60 + lane] = acc;
    }
}

// ---------------- launch ----------------

extern "C" void kernel_launch(void* const* d_in, const int* in_sizes, int n_in,
                              void* d_out, int out_size, void* d_ws, size_t ws_size,
                              hipStream_t stream) {
    const float* x          = (const float*)d_in[0];
    const float* lane_x     = (const float*)d_in[1];
    const float* centerline = (const float*)d_in[2];
    const int*   ei         = (const int*)d_in[3];
    const int*   focal_idx  = (const int*)d_in[4];
    const float* emb_W = (const float*)d_in[5];
    const float* emb_b = (const float*)d_in[6];
    const float* c1_Wl = (const float*)d_in[7];
    const float* c1_Wr = (const float*)d_in[8];
    const float* c1_att = (const float*)d_in[9];
    const float* c1_b  = (const float*)d_in[10];
    const float* c2_Wl = (const float*)d_in[11];
    const float* c2_Wr = (const float*)d_in[12];
    const float* c2_att = (const float*)d_in[13];
    const float* c2_b  = (const float*)d_in[14];
    const float* map_W = (const float*)d_in[15];
    const float* map_b = (const float*)d_in[16];
    const float* gg_Wl = (const float*)d_in[17];
    const float* gg_Wr = (const float*)d_in[18];
    const float* gg_att = (const float*)d_in[19];
    const float* gg_b  = (const float*)d_in[20];
    const float* cl_W  = (const float*)d_in[21];
    const float* cl_b  = (const float*)d_in[22];
    const float* fc1_W = (const float*)d_in[23];
    const float* fc1_b = (const float*)d_in[24];
    const float* fc2_W = (const float*)d_in[25];
    const float* fc2_b = (const float*)d_in[26];
    const float* fco_W = (const float*)d_in[27];
    const float* fco_b = (const float*)d_in[28];

    const int N = in_sizes[0] / 60;
    const int M = in_sizes[1] / 2;
    const int F = in_sizes[4];
    const int L = in_sizes[2] / (F * 2);
    const int E = in_sizes[3] / 2;
    const int Etot = E + N;
    const int n8 = N * NBKT;

    // Workspace layout:
    half_t* Xl_h = (half_t*)d_ws;                    // N*128
    half_t* Xr_h = Xl_h + (size_t)N * 128;           // N*128
    half_t* H0_h = Xr_h + (size_t)N * 128;           // N*32
    half_t* H1_h = H0_h + (size_t)N * 32;            // N*128
    half_t* AF_h = H1_h + (size_t)N * 128;           // N*128
    float*  GF_f = (float*)(AF_h + (size_t)N * 128); // N*32 f32
    half_t* Wt   = (half_t*)(GF_f + (size_t)N * 32); // 49440 halfs
    int* counts8  = (int*)(Wt + 49440);              // 8N
    int* offsets8 = counts8 + n8;                     // 8N
    int* cursor8  = offsets8 + n8;                    // 8N
    int* adj      = cursor8 + n8;                     // Etot
    float* MAPS   = (float*)(adj + Etot);             // 32
    int* partial  = (int*)(MAPS + 32);                // nch

    half_t* c1Wlt = Wt + 0;
    half_t* c1Wrt = Wt + 4096;
    half_t* c2Wlt = Wt + 8192;
    half_t* c2Wrt = Wt + 24576;
    half_t* ggWlt = Wt + 40960;
    half_t* ggWrt = Wt + 45056;
    half_t* att1h = Wt + 49152;
    half_t* att2h = Wt + 49280;
    half_t* attgh = Wt + 49408;

    const int BS = 256;
    const int nch = cdiv(n8, SCAN_CH);
    const int rowBlocks = cdiv(N, 128);
    const int sliceSz = cdiv(N, 8);

    // ---- CSR build (src-bucketed; self-loops as ordinary edges) ----
    hipMemsetAsync(counts8, 0, (size_t)n8 * sizeof(int), stream);
    count_dst8<<<cdiv(Etot, BS), BS, 0, stream>>>(ei, counts8, E, N);
    reduce_chunks<<<nch, 256, 0, stream>>>(counts8, partial, n8);
    scan_partials<<<1, 64, 0, stream>>>(partial, nch);
    scan_chunks<<<nch, 256, 0, stream>>>(counts8, partial, offsets8, cursor8, n8);
    fill_adj_sliced<<<8 * 104, 256, 0, stream>>>(ei, cursor8, adj, E, N, sliceSz);

    // ---- weights + att -> f16 ----
    wtrans<<<cdiv(49440, BS), BS, 0, stream>>>(c1_Wl, c1_Wr, c2_Wl, c2_Wr, gg_Wl, gg_Wr,
                                               c1_att, c2_att, gg_att, Wt);

    // ---- h0 = relu(x @ emb_W + emb_b) -> H0_h ----
    gemm_t_h<15, 8, 4><<<cdiv((long)(N / 4) * 8, BS), BS, 0, stream>>>(x, emb_W, emb_b, H0_h, N, 1);

    // ---- layer 1 (H=4) ----
    mfma_dual<32, 128><<<rowBlocks * 4, 256, 0, stream>>>(H0_h, c1Wlt, c1Wrt, Xl_h, Xr_h, N);
    gat16_h4<<<cdiv(N, 16), 256, 0, stream>>>(Xl_h, Xr_h, att1h, offsets8, adj, c1_b, H1_h, N, Etot);

    // ---- layer 2 (H=4) ----
    mfma_dual<128, 128><<<rowBlocks * 4, 256, 0, stream>>>(H1_h, c2Wlt, c2Wrt, Xl_h, Xr_h, N);
    gat16_h4<<<cdiv(N, 16), 256, 0, stream>>>(Xl_h, Xr_h, att2h, offsets8, adj, c2_b, AF_h, N, Etot);

    // ---- global graph (H=1) ----
    mfma_dual<128, 32><<<rowBlocks * 1, 256, 0, stream>>>(AF_h, ggWlt, ggWrt, Xl_h, Xr_h, N);
    gat16_h1<<<cdiv(N, 16), 256, 0, stream>>>(Xl_h, Xr_h, attgh, offsets8, adj, gg_b, GF_f, N, Etot);

    // ---- map branch ----
    hipMemsetAsync(MAPS, 0, 32 * sizeof(float), stream);
    map_sum_kernel<<<64, BS, 0, stream>>>(lane_x, map_W, map_b, MAPS, M);

    // ---- fused head ----
    head_kernel<<<F, 64, 0, stream>>>(GF_f, focal_idx, MAPS, M, centerline, L,
                                      cl_W, cl_b, fc1_W, fc1_b, fc2_W, fc2_b,
                                      fco_W, fco_b, (float*)d_out);
}

// Round 4
// 381.101 us; speedup vs baseline: 1.0987x; 1.0273x over previous
//
#include <hip/hip_runtime.h>
#include <hip/hip_bf16.h>
#include <hip/hip_fp16.h>

typedef _Float16 half_t;
typedef _Float16 h8 __attribute__((ext_vector_type(8)));
typedef _Float16 h4v __attribute__((ext_vector_type(4)));
typedef _Float16 h2v __attribute__((ext_vector_type(2)));
typedef float f4v __attribute__((ext_vector_type(4)));

union H8u { h8 v; h2v h2[4]; _Float16 e[8]; };
union H4u { h4v v; h2v h2[2]; _Float16 e[4]; };

static inline int cdiv(long a, long b) { return (int)((a + b - 1) / b); }

__device__ __forceinline__ void fma4(float4& a, float s, const float4& w) {
    a.x += s * w.x; a.y += s * w.y; a.z += s * w.z; a.w += s * w.w;
}

__device__ __forceinline__ h8 hmax8(h8 a, h8 b) {
#if __has_builtin(__builtin_elementwise_max)
    return __builtin_elementwise_max(a, b);
#else
    h8 r;
#pragma unroll
    for (int j = 0; j < 8; ++j) r[j] = (a[j] > b[j]) ? a[j] : b[j];
    return r;
#endif
}
__device__ __forceinline__ h4v hmax4(h4v a, h4v b) {
#if __has_builtin(__builtin_elementwise_max)
    return __builtin_elementwise_max(a, b);
#else
    h4v r;
#pragma unroll
    for (int j = 0; j < 4; ++j) r[j] = (a[j] > b[j]) ? a[j] : b[j];
    return r;
#endif
}

__device__ __forceinline__ float dot2acc(h2v a, h2v b, float c) {
#if __has_builtin(__builtin_amdgcn_fdot2)
    return __builtin_amdgcn_fdot2(a, b, c, false);
#else
    return c + (float)a.x * (float)b.x + (float)a.y * (float)b.y;
#endif
}

// ---------------- emb GEMM (fp32 compute, fp16 out) ----------------

template <int K4, int C4, int R>
__global__ __launch_bounds__(256) void gemm_t_h(
        const float* __restrict__ X, const float* __restrict__ W,
        const float* __restrict__ bias, half_t* __restrict__ Y,
        int Nr, int relu) {
    int idx = blockIdx.x * blockDim.x + threadIdx.x;
    int total = (Nr / R) * C4;
    if (idx >= total) return;
    int c4 = idx % C4;
    int n0 = (idx / C4) * R;
    const float4* __restrict__ Wv = (const float4*)W;
    const float4* __restrict__ Xv = (const float4*)X;
    float4 acc[R];
    float4 binit = bias ? ((const float4*)bias)[c4] : make_float4(0.f, 0.f, 0.f, 0.f);
#pragma unroll
    for (int r = 0; r < R; ++r) acc[r] = binit;
#pragma unroll 4
    for (int k4 = 0; k4 < K4; ++k4) {
        float4 w0 = Wv[(size_t)(4 * k4 + 0) * C4 + c4];
        float4 w1 = Wv[(size_t)(4 * k4 + 1) * C4 + c4];
        float4 w2 = Wv[(size_t)(4 * k4 + 2) * C4 + c4];
        float4 w3 = Wv[(size_t)(4 * k4 + 3) * C4 + c4];
#pragma unroll
        for (int r = 0; r < R; ++r) {
            float4 xv = Xv[(size_t)(n0 + r) * K4 + k4];
            fma4(acc[r], xv.x, w0); fma4(acc[r], xv.y, w1);
            fma4(acc[r], xv.z, w2); fma4(acc[r], xv.w, w3);
        }
    }
#pragma unroll
    for (int r = 0; r < R; ++r) {
        float4 o = acc[r];
        if (relu) {
            o.x = fmaxf(o.x, 0.f); o.y = fmaxf(o.y, 0.f);
            o.z = fmaxf(o.z, 0.f); o.w = fmaxf(o.w, 0.f);
        }
        h4v oh; oh.x = (half_t)o.x; oh.y = (half_t)o.y; oh.z = (half_t)o.z; oh.w = (half_t)o.w;
        ((h4v*)Y)[(size_t)(n0 + r) * C4 + c4] = oh;
    }
}

// ---------------- weight transpose+convert + att convert + MAPS zero ----------------

__global__ void wtrans(const float* __restrict__ c1l, const float* __restrict__ c1r,
                       const float* __restrict__ c2l, const float* __restrict__ c2r,
                       const float* __restrict__ ggl, const float* __restrict__ ggr,
                       const float* __restrict__ at1, const float* __restrict__ at2,
                       const float* __restrict__ atg, half_t* __restrict__ dst,
                       float* __restrict__ maps) {
    int idx = blockIdx.x * blockDim.x + threadIdx.x;
    if (idx >= 49472) return;
    if (idx >= 49440) { maps[idx - 49440] = 0.f; return; }  // zero MAPS (drops a memset dispatch)
    if (idx >= 49152) {
        int j = idx - 49152;
        float v = (j < 128) ? at1[j] : (j < 256) ? at2[j - 128] : atg[j - 256];
        dst[idx] = (half_t)v;
        return;
    }
    const float* src; int K, loc;
    if (idx < 8192) {
        K = 32;
        if (idx < 4096) { src = c1l; loc = idx; } else { src = c1r; loc = idx - 4096; }
        int k = loc % K, c = loc / K;
        dst[idx] = (half_t)src[k * 128 + c];
    } else if (idx < 40960) {
        K = 128;
        if (idx < 24576) { src = c2l; loc = idx - 8192; } else { src = c2r; loc = idx - 24576; }
        int k = loc % K, c = loc / K;
        dst[idx] = (half_t)src[k * 128 + c];
    } else {
        K = 128;
        if (idx < 45056) { src = ggl; loc = idx - 40960; } else { src = ggr; loc = idx - 45056; }
        int k = loc % K, c = loc / K;
        dst[idx] = (half_t)src[k * 32 + c];
    }
}

// ---------------- MFMA dual GEMM ----------------
// R16: CB col-blocks (of 64 cols) per block -> A-fragments loaded once per
// kk serve 2x the output columns, halving A-panel re-reads (51->26 MB for
// the K=128 GEMM).

template <int K, int C1, int CB>
__global__ __launch_bounds__(256) void mfma_dual(
        const half_t* __restrict__ Xh,
        const half_t* __restrict__ W1t, const half_t* __restrict__ W2t,
        half_t* __restrict__ Y1, half_t* __restrict__ Y2, int Nr) {
    constexpr int KT = K / 32;
    constexpr int NBC = (2 * C1) / 64;   // total 64-col blocks
    constexpr int NBG = NBC / CB;        // grid col dimension
    int wave = threadIdx.x >> 6, lane = threadIdx.x & 63;
    int bCol = blockIdx.x % NBG;
    int bRow = blockIdx.x / NBG;
    int rowBase = bRow * 128 + wave * 32;
    int m = lane & 15, quad = lane >> 4;

    f4v acc[CB][2][4] = {};

    const half_t* bptr[CB][4];
#pragma unroll
    for (int cb = 0; cb < CB; ++cb) {
        int colBase = (bCol * CB + cb) * 64;
#pragma unroll
        for (int nt = 0; nt < 4; ++nt) {
            int gc = colBase + nt * 16 + m;
            bptr[cb][nt] = (gc < C1) ? (W1t + (size_t)gc * K) : (W2t + (size_t)(gc - C1) * K);
        }
    }
    int r0 = rowBase + m, r1 = rowBase + 16 + m;
    int r0c = (r0 < Nr) ? r0 : (Nr - 1);
    int r1c = (r1 < Nr) ? r1 : (Nr - 1);
    const half_t* a0p = Xh + (size_t)r0c * K + quad * 8;
    const half_t* a1p = Xh + (size_t)r1c * K + quad * 8;

#pragma unroll
    for (int kk = 0; kk < KT; ++kk) {
        h8 a0 = *(const h8*)(a0p + kk * 32);
        h8 a1 = *(const h8*)(a1p + kk * 32);
#pragma unroll
        for (int cb = 0; cb < CB; ++cb) {
#pragma unroll
            for (int nt = 0; nt < 4; ++nt) {
                h8 b = *(const h8*)(bptr[cb][nt] + kk * 32 + quad * 8);
                acc[cb][0][nt] = __builtin_amdgcn_mfma_f32_16x16x32_f16(a0, b, acc[cb][0][nt], 0, 0, 0);
                acc[cb][1][nt] = __builtin_amdgcn_mfma_f32_16x16x32_f16(a1, b, acc[cb][1][nt], 0, 0, 0);
            }
        }
    }

#pragma unroll
    for (int cb = 0; cb < CB; ++cb) {
        int colBase = (bCol * CB + cb) * 64;
#pragma unroll
        for (int mt = 0; mt < 2; ++mt) {
#pragma unroll
            for (int nt = 0; nt < 4; ++nt) {
                int gc = colBase + nt * 16 + m;
                half_t* Y = (gc < C1) ? (Y1 + gc) : (Y2 + (gc - C1));
#pragma unroll
                for (int r = 0; r < 4; ++r) {
                    int gr = rowBase + mt * 16 + quad * 4 + r;
                    if (gr < Nr) Y[(size_t)gr * C1] = (half_t)acc[cb][mt][nt][r];
                }
            }
        }
    }
}

// ---------------- CSR construction ----------------
// Self-loops prefilled in scan_chunks; count_dst/fill_adj touch only E real edges.

__global__ void count_dst(const int* __restrict__ ei, int* __restrict__ counts, int E) {
    int e = blockIdx.x * blockDim.x + threadIdx.x;
    if (e >= E) return;
    atomicAdd(&counts[ei[E + e]], 1);
}

#define SCAN_CH 2048  // 256 threads x 8

__global__ void reduce_chunks(const int* __restrict__ counts, int* __restrict__ partial, int N) {
    __shared__ int sh[256];
    int t = threadIdx.x, base = blockIdx.x * SCAN_CH + t * 8;
    int s = 0;
    for (int j = 0; j < 8; ++j) if (base + j < N) s += counts[base + j] + 1;  // +1 self-loop
    sh[t] = s; __syncthreads();
    for (int off = 128; off >= 1; off >>= 1) {
        if (t < off) sh[t] += sh[t + off];
        __syncthreads();
    }
    if (t == 0) partial[blockIdx.x] = sh[0];
}

__global__ void scan_partials(int* __restrict__ partial, int nch) {
    if (threadIdx.x == 0 && blockIdx.x == 0) {
        int run = 0;
        for (int i = 0; i < nch; ++i) { int v = partial[i]; partial[i] = run; run += v; }
    }
}

// Writes offsets; seeds cursor past the self-loop; prefills the self-loop
// into adj; updates counts to true degree (incl. self-loop).
__global__ void scan_chunks(int* __restrict__ counts, const int* __restrict__ partial,
                            int* __restrict__ offsets, int* __restrict__ cursor,
                            int* __restrict__ adj, int N) {
    __shared__ int sh[256];
    int t = threadIdx.x, b = blockIdx.x, base = b * SCAN_CH + t * 8;
    int v[8], s = 0;
    for (int j = 0; j < 8; ++j) {
        v[j] = (base + j < N) ? (counts[base + j] + 1) : 0;
        s += v[j];
    }
    sh[t] = s; __syncthreads();
    for (int off = 1; off < 256; off <<= 1) {
        int x = (t >= off) ? sh[t - off] : 0;
        __syncthreads();
        sh[t] += x;
        __syncthreads();
    }
    int run = partial[b] + (t == 0 ? 0 : sh[t - 1]);
    for (int j = 0; j < 8; ++j) {
        if (base + j < N) {
            offsets[base + j] = run;
            adj[run] = base + j;       // self-loop first
            cursor[base + j] = run + 1;
            counts[base + j] = v[j];   // true degree (incl. self-loop)
        }
        run += v[j];
    }
}

// XCD-sliced adj scatter (verified R12: removed fill_adj's 53 MB write-back
// amplification). Block b handles dst slice b&7 (blockIdx%8 ~ XCD round-robin),
// so all stores to one adj region write-combine in one XCD's L2.
__global__ __launch_bounds__(256) void fill_adj_sliced(
        const int* __restrict__ ei, int* __restrict__ cursor,
        int* __restrict__ adj, int E, int sliceSz) {
    int slice = blockIdx.x & 7;
    int lo = slice * sliceSz, hi = lo + sliceSz;
    int nb = gridDim.x >> 3;          // blocks per slice
    int bi = blockIdx.x >> 3;
    int stride = nb * 256;
    for (int e = bi * 256 + threadIdx.x; e < E; e += stride) {
        int d = ei[E + e];
        if (d >= lo && d < hi) {
            int pos = atomicAdd(&cursor[d], 1);
            adj[pos] = ei[e];
        }
    }
}

// ---------------- fused GATv2 ----------------
// 16 lanes/dst (8 halfs each), 4 dsts/wave -> 12500 waves, unroll x4 with
// software-pipelined adj index prefetch. R14/R15 verdict: list ORDER is
// worth ~0 (FETCH is at the distinct-row floor; L2 already captures all
// intra-XCD reuse; gather runs at the ~2.45 TB/s random-row path ceiling) --
// so no sorting/bucketing, plain CSR.

__global__ __launch_bounds__(256) void gat16_h4(
        const half_t* __restrict__ xl, const half_t* __restrict__ xr,
        const half_t* __restrict__ atth, const int* __restrict__ offsets,
        const int* __restrict__ counts, const int* __restrict__ adj,
        const float* __restrict__ bias, half_t* __restrict__ out, int N) {
    int wave = threadIdx.x >> 6, lane = threadIdx.x & 63;
    int g = lane >> 4, t = lane & 15;
    int d = blockIdx.x * 16 + wave * 4 + g;
    int dc = (d < N) ? d : (N - 1);
    int off = offsets[dc];
    int deg = (d < N) ? counts[dc] : 0;
    int dmax = deg;
    dmax = max(dmax, __shfl_xor(dmax, 16));
    dmax = max(dmax, __shfl_xor(dmax, 32));

    h8 xr8 = *(const h8*)(xr + (size_t)dc * 128 + t * 8);
    H8u at8; at8.v = *(const h8*)(atth + t * 8);

    float acc[8];
#pragma unroll
    for (int j = 0; j < 8; ++j) acc[j] = 0.f;
    float lsum = 0.f;
    h8 c02;
#pragma unroll
    for (int j = 0; j < 8; ++j) c02[j] = (half_t)0.2f;

    bool v0 = 0 < deg, v1 = 1 < deg, v2 = 2 < deg, v3 = 3 < deg;
    int s0 = adj[off];
    int s1 = adj[off + (v1 ? 1 : 0)];
    int s2 = adj[off + (v2 ? 2 : 0)];
    int s3 = adj[off + (v3 ? 3 : 0)];

    for (int i = 0; i < dmax; i += 4) {
        H8u a0, a1, a2, a3;
        a0.v = *(const h8*)(xl + (size_t)s0 * 128 + t * 8);
        a1.v = *(const h8*)(xl + (size_t)s1 * 128 + t * 8);
        a2.v = *(const h8*)(xl + (size_t)s2 * 128 + t * 8);
        a3.v = *(const h8*)(xl + (size_t)s3 * 128 + t * 8);
        // prefetch next iteration's indices while the gathers are in flight
        int ni = i + 4;
        bool nv0 = ni < deg, nv1 = ni + 1 < deg, nv2 = ni + 2 < deg, nv3 = ni + 3 < deg;
        int n0 = adj[off + (nv0 ? ni : 0)];
        int n1 = adj[off + (nv1 ? ni + 1 : 0)];
        int n2 = adj[off + (nv2 ? ni + 2 : 0)];
        int n3 = adj[off + (nv3 ? ni + 3 : 0)];

        h8 e0 = a0.v + xr8, e1 = a1.v + xr8, e2 = a2.v + xr8, e3 = a3.v + xr8;
        H8u l0, l1, l2, l3;
        l0.v = hmax8(e0, e0 * c02);
        l1.v = hmax8(e1, e1 * c02);
        l2.v = hmax8(e2, e2 * c02);
        l3.v = hmax8(e3, e3 * c02);
        float p0 = 0.f, p1 = 0.f, p2 = 0.f, p3 = 0.f;
#pragma unroll
        for (int j = 0; j < 4; ++j) {
            p0 = dot2acc(l0.h2[j], at8.h2[j], p0);
            p1 = dot2acc(l1.h2[j], at8.h2[j], p1);
            p2 = dot2acc(l2.h2[j], at8.h2[j], p2);
            p3 = dot2acc(l3.h2[j], at8.h2[j], p3);
        }
        // head = t>>2; sum the 4 lanes (32 channels) of this head
        p0 += __shfl_xor(p0, 1); p1 += __shfl_xor(p1, 1);
        p2 += __shfl_xor(p2, 1); p3 += __shfl_xor(p3, 1);
        p0 += __shfl_xor(p0, 2); p1 += __shfl_xor(p1, 2);
        p2 += __shfl_xor(p2, 2); p3 += __shfl_xor(p3, 2);
        float w0 = v0 ? __expf(p0) : 0.f;
        float w1 = v1 ? __expf(p1) : 0.f;
        float w2 = v2 ? __expf(p2) : 0.f;
        float w3 = v3 ? __expf(p3) : 0.f;
        lsum += (w0 + w1) + (w2 + w3);
#pragma unroll
        for (int j = 0; j < 8; ++j)
            acc[j] += w0 * (float)a0.e[j] + w1 * (float)a1.e[j]
                    + w2 * (float)a2.e[j] + w3 * (float)a3.e[j];
        s0 = n0; s1 = n1; s2 = n2; s3 = n3;
        v0 = nv0; v1 = nv1; v2 = nv2; v3 = nv3;
    }

    if (d < N) {
        float inv = 1.f / lsum;
        H8u o;
#pragma unroll
        for (int j = 0; j < 8; ++j)
            o.e[j] = (half_t)fmaxf(acc[j] * inv + bias[t * 8 + j], 0.f);
        *(h8*)(out + (size_t)d * 128 + t * 8) = o.v;
    }
}

// H=1, 32 features. 16 lanes/dst as two 8-lane subgroups; subgroup `sub`
// processes edges i ≡ sub (mod 2) with 4 chains + adj prefetch -> 8 edges in
// flight per dst. Partials combined across subgroups with shfl_xor(8).
__global__ __launch_bounds__(256) void gat16_h1(
        const half_t* __restrict__ xl, const half_t* __restrict__ xr,
        const half_t* __restrict__ atth, const int* __restrict__ offsets,
        const int* __restrict__ counts, const int* __restrict__ adj,
        const float* __restrict__ bias, float* __restrict__ out, int N) {
    int wave = threadIdx.x >> 6, lane = threadIdx.x & 63;
    int g = lane >> 4, sub = (lane >> 3) & 1, t = lane & 7;
    int d = blockIdx.x * 16 + wave * 4 + g;
    int dc = (d < N) ? d : (N - 1);
    int off = offsets[dc];
    int deg = (d < N) ? counts[dc] : 0;
    int dmax = deg;
    dmax = max(dmax, __shfl_xor(dmax, 16));
    dmax = max(dmax, __shfl_xor(dmax, 32));

    h4v xr4 = *(const h4v*)(xr + (size_t)dc * 32 + t * 4);
    H4u at4; at4.v = *(const h4v*)(atth + t * 4);

    float acc[4] = {0.f, 0.f, 0.f, 0.f};
    float lsum = 0.f;
    h4v c02;
#pragma unroll
    for (int j = 0; j < 4; ++j) c02[j] = (half_t)0.2f;

    int i = sub;
    bool va = i < deg, vb = i + 2 < deg, vc = i + 4 < deg, vd = i + 6 < deg;
    int sa = adj[off + (va ? i : 0)];
    int sb = adj[off + (vb ? i + 2 : 0)];
    int sc = adj[off + (vc ? i + 4 : 0)];
    int sd = adj[off + (vd ? i + 6 : 0)];
    for (; i < dmax; i += 8) {
        H4u a, b, c, e;
        a.v = *(const h4v*)(xl + (size_t)sa * 32 + t * 4);
        b.v = *(const h4v*)(xl + (size_t)sb * 32 + t * 4);
        c.v = *(const h4v*)(xl + (size_t)sc * 32 + t * 4);
        e.v = *(const h4v*)(xl + (size_t)sd * 32 + t * 4);
        int ni = i + 8;
        bool nva = ni < deg, nvb = ni + 2 < deg, nvc = ni + 4 < deg, nvd = ni + 6 < deg;
        int na = adj[off + (nva ? ni : 0)];
        int nb = adj[off + (nvb ? ni + 2 : 0)];
        int nc = adj[off + (nvc ? ni + 4 : 0)];
        int nd = adj[off + (nvd ? ni + 6 : 0)];
        h4v ea = a.v + xr4, eb = b.v + xr4, ec = c.v + xr4, ed = e.v + xr4;
        H4u la, lb, lc, ld;
        la.v = hmax4(ea, ea * c02);
        lb.v = hmax4(eb, eb * c02);
        lc.v = hmax4(ec, ec * c02);
        ld.v = hmax4(ed, ed * c02);
        float pa = dot2acc(la.h2[0], at4.h2[0], 0.f);
        float pb = dot2acc(lb.h2[0], at4.h2[0], 0.f);
        float pc = dot2acc(lc.h2[0], at4.h2[0], 0.f);
        float pd = dot2acc(ld.h2[0], at4.h2[0], 0.f);
        pa = dot2acc(la.h2[1], at4.h2[1], pa);
        pb = dot2acc(lb.h2[1], at4.h2[1], pb);
        pc = dot2acc(lc.h2[1], at4.h2[1], pc);
        pd = dot2acc(ld.h2[1], at4.h2[1], pd);
        pa += __shfl_xor(pa, 1); pb += __shfl_xor(pb, 1);
        pc += __shfl_xor(pc, 1); pd += __shfl_xor(pd, 1);
        pa += __shfl_xor(pa, 2); pb += __shfl_xor(pb, 2);
        pc += __shfl_xor(pc, 2); pd += __shfl_xor(pd, 2);
        pa += __shfl_xor(pa, 4); pb += __shfl_xor(pb, 4);
        pc += __shfl_xor(pc, 4); pd += __shfl_xor(pd, 4);
        float wa = va ? __expf(pa) : 0.f;
        float wb = vb ? __expf(pb) : 0.f;
        float wc = vc ? __expf(pc) : 0.f;
        float wd = vd ? __expf(pd) : 0.f;
        lsum += (wa + wb) + (wc + wd);
#pragma unroll
        for (int j = 0; j < 4; ++j)
            acc[j] += wa * (float)a.e[j] + wb * (float)b.e[j]
                    + wc * (float)c.e[j] + wd * (float)e.e[j];
        sa = na; sb = nb; sc = nc; sd = nd;
        va = nva; vb = nvb; vc = nvc; vd = nvd;
    }

    // combine the two subgroups (differ only in lane bit 3)
    lsum += __shfl_xor(lsum, 8);
#pragma unroll
    for (int j = 0; j < 4; ++j) acc[j] += __shfl_xor(acc[j], 8);

    if (d < N && sub == 0) {
        float inv = 1.f / lsum;
        float4 o;
        o.x = fmaxf(acc[0] * inv + bias[t * 4 + 0], 0.f);
        o.y = fmaxf(acc[1] * inv + bias[t * 4 + 1], 0.f);
        o.z = fmaxf(acc[2] * inv + bias[t * 4 + 2], 0.f);
        o.w = fmaxf(acc[3] * inv + bias[t * 4 + 3], 0.f);
        *(float4*)(out + (size_t)d * 32 + t * 4) = o;
    }
}

// ---------------- map branch ----------------

__global__ void map_sum_kernel(const float* __restrict__ lane_x, const float* __restrict__ map_W,
                               const float* __restrict__ map_b, float* __restrict__ sums, int M) {
    __shared__ float s[32];
    if (threadIdx.x < 32) s[threadIdx.x] = 0.f;
    __syncthreads();
    int t = blockIdx.x * blockDim.x + threadIdx.x;
    int nth = gridDim.x * blockDim.x;
    int c = t & 31;
    float w0 = map_W[c], w1 = map_W[32 + c], bb = map_b[c];
    float acc = 0.f;
    for (int m = t >> 5; m < M; m += nth >> 5) {
        float v = lane_x[(long)m * 2] * w0 + lane_x[(long)m * 2 + 1] * w1 + bb;
        acc += fmaxf(v, 0.f);
    }
    atomicAdd(&s[c], acc);
    __syncthreads();
    if (threadIdx.x < 32) atomicAdd(&sums[threadIdx.x], s[threadIdx.x]);
}

// ---------------- fused head ----------------

__global__ void head_kernel(const float* __restrict__ gf, const int* __restrict__ focal_idx,
                            const float* __restrict__ map_sums, int M,
                            const float* __restrict__ centerline, int L,
                            const float* __restrict__ cl_W, const float* __restrict__ cl_b,
                            const float* __restrict__ fc1_W, const float* __restrict__ fc1_b,
                            const float* __restrict__ fc2_W, const float* __restrict__ fc2_b,
                            const float* __restrict__ fco_W, const float* __restrict__ fco_b,
                            float* __restrict__ out) {
    int f = blockIdx.x;
    int lane = threadIdx.x;
    __shared__ float s_comb[96];
    __shared__ float s_h1[32];
    __shared__ float s_h2[16];
    __shared__ float s_cl[2];

    float c0 = 0.f, c1 = 0.f;
    if (lane < L) {
        c0 = centerline[((long)f * L + lane) * 2 + 0];
        c1 = centerline[((long)f * L + lane) * 2 + 1];
    }
    for (int off = 32; off >= 1; off >>= 1) {
        c0 += __shfl_down(c0, off);
        c1 += __shfl_down(c1, off);
    }
    if (lane == 0) { s_cl[0] = c0 / (float)L; s_cl[1] = c1 / (float)L; }
    __syncthreads();

    int fi = focal_idx[f];
    if (lane < 32) {
        s_comb[lane] = gf[(long)fi * 32 + lane];
        s_comb[32 + lane] = map_sums[lane] / (float)M;
        s_comb[64 + lane] = s_cl[0] * cl_W[lane] + s_cl[1] * cl_W[32 + lane] + cl_b[lane];
    }
    __syncthreads();

    if (lane < 32) {
        float acc = fc1_b[lane];
        for (int k = 0; k < 96; ++k) acc += s_comb[k] * fc1_W[k * 32 + lane];
        s_h1[lane] = fmaxf(acc, 0.f);
    }
    __syncthreads();

    if (lane < 16) {
        float acc = fc2_b[lane];
        for (int k = 0; k < 32; ++k) acc += s_h1[k] * fc2_W[k * 16 + lane];
        s_h2[lane] = fmaxf(acc, 0.f);
    }
    __syncthreads();

    if (lane < 60) {
        float acc = fco_b[lane];
        for (int k = 0; k < 16; ++k) acc += s_h2[k] * fco_W[k * 60 + lane];
        out[(long)f * 60 + lane] = acc;
    }
}

// ---------------- launch ----------------

extern "C" void kernel_launch(void* const* d_in, const int* in_sizes, int n_in,
                              void* d_out, int out_size, void* d_ws, size_t ws_size,
                              hipStream_t stream) {
    const float* x          = (const float*)d_in[0];
    const float* lane_x     = (const float*)d_in[1];
    const float* centerline = (const float*)d_in[2];
    const int*   ei         = (const int*)d_in[3];
    const int*   focal_idx  = (const int*)d_in[4];
    const float* emb_W = (const float*)d_in[5];
    const float* emb_b = (const float*)d_in[6];
    const float* c1_Wl = (const float*)d_in[7];
    const float* c1_Wr = (const float*)d_in[8];
    const float* c1_att = (const float*)d_in[9];
    const float* c1_b  = (const float*)d_in[10];
    const float* c2_Wl = (const float*)d_in[11];
    const float* c2_Wr = (const float*)d_in[12];
    const float* c2_att = (const float*)d_in[13];
    const float* c2_b  = (const float*)d_in[14];
    const float* map_W = (const float*)d_in[15];
    const float* map_b = (const float*)d_in[16];
    const float* gg_Wl = (const float*)d_in[17];
    const float* gg_Wr = (const float*)d_in[18];
    const float* gg_att = (const float*)d_in[19];
    const float* gg_b  = (const float*)d_in[20];
    const float* cl_W  = (const float*)d_in[21];
    const float* cl_b  = (const float*)d_in[22];
    const float* fc1_W = (const float*)d_in[23];
    const float* fc1_b = (const float*)d_in[24];
    const float* fc2_W = (const float*)d_in[25];
    const float* fc2_b = (const float*)d_in[26];
    const float* fco_W = (const float*)d_in[27];
    const float* fco_b = (const float*)d_in[28];

    const int N = in_sizes[0] / 60;
    const int M = in_sizes[1] / 2;
    const int F = in_sizes[4];
    const int L = in_sizes[2] / (F * 2);
    const int E = in_sizes[3] / 2;
    const int Etot = E + N;

    // Workspace layout:
    half_t* Xl_h = (half_t*)d_ws;                    // N*128
    half_t* Xr_h = Xl_h + (size_t)N * 128;           // N*128
    half_t* H0_h = Xr_h + (size_t)N * 128;           // N*32
    half_t* H1_h = H0_h + (size_t)N * 32;            // N*128
    half_t* AF_h = H1_h + (size_t)N * 128;           // N*128
    float*  GF_f = (float*)(AF_h + (size_t)N * 128); // N*32 f32
    half_t* Wt   = (half_t*)(GF_f + (size_t)N * 32); // 49440 halfs
    int* counts  = (int*)(Wt + 49440);               // N
    int* offsets = counts + N;                        // N
    int* cursor  = offsets + N;                       // N
    int* adj     = cursor + N;                        // Etot
    float* MAPS  = (float*)(adj + Etot);              // 32
    int* partial = (int*)(MAPS + 32);                 // nch

    half_t* c1Wlt = Wt + 0;
    half_t* c1Wrt = Wt + 4096;
    half_t* c2Wlt = Wt + 8192;
    half_t* c2Wrt = Wt + 24576;
    half_t* ggWlt = Wt + 40960;
    half_t* ggWrt = Wt + 45056;
    half_t* att1h = Wt + 49152;
    half_t* att2h = Wt + 49280;
    half_t* attgh = Wt + 49408;

    const int BS = 256;
    const int nch = cdiv(N, SCAN_CH);
    const int rowBlocks = cdiv(N, 128);
    const int sliceSz = cdiv(N, 8);

    // ---- CSR build (self-loops prefilled in scan_chunks; XCD-sliced scatter) ----
    hipMemsetAsync(counts, 0, (size_t)N * sizeof(int), stream);
    count_dst<<<cdiv(E, BS), BS, 0, stream>>>(ei, counts, E);
    reduce_chunks<<<nch, 256, 0, stream>>>(counts, partial, N);
    scan_partials<<<1, 64, 0, stream>>>(partial, nch);
    scan_chunks<<<nch, 256, 0, stream>>>(counts, partial, offsets, cursor, adj, N);
    fill_adj_sliced<<<8 * 104, 256, 0, stream>>>(ei, cursor, adj, E, sliceSz);

    // ---- weights + att -> f16 (also zeroes MAPS) ----
    wtrans<<<cdiv(49472, BS), BS, 0, stream>>>(c1_Wl, c1_Wr, c2_Wl, c2_Wr, gg_Wl, gg_Wr,
                                               c1_att, c2_att, gg_att, Wt, MAPS);

    // ---- h0 = relu(x @ emb_W + emb_b) -> H0_h ----
    gemm_t_h<15, 8, 4><<<cdiv((long)(N / 4) * 8, BS), BS, 0, stream>>>(x, emb_W, emb_b, H0_h, N, 1);

    // ---- layer 1 (H=4) ----
    mfma_dual<32, 128, 2><<<rowBlocks * 2, 256, 0, stream>>>(H0_h, c1Wlt, c1Wrt, Xl_h, Xr_h, N);
    gat16_h4<<<cdiv(N, 16), 256, 0, stream>>>(Xl_h, Xr_h, att1h, offsets, counts, adj, c1_b, H1_h, N);

    // ---- layer 2 (H=4) ----
    mfma_dual<128, 128, 2><<<rowBlocks * 2, 256, 0, stream>>>(H1_h, c2Wlt, c2Wrt, Xl_h, Xr_h, N);
    gat16_h4<<<cdiv(N, 16), 256, 0, stream>>>(Xl_h, Xr_h, att2h, offsets, counts, adj, c2_b, AF_h, N);

    // ---- global graph (H=1) ----
    mfma_dual<128, 32, 1><<<rowBlocks * 1, 256, 0, stream>>>(AF_h, ggWlt, ggWrt, Xl_h, Xr_h, N);
    gat16_h1<<<cdiv(N, 16), 256, 0, stream>>>(Xl_h, Xr_h, attgh, offsets, counts, adj, gg_b, GF_f, N);

    // ---- map branch (MAPS zeroed by wtrans above) ----
    map_sum_kernel<<<64, BS, 0, stream>>>(lane_x, map_W, map_b, MAPS, M);

    // ---- fused head ----
    head_kernel<<<F, 64, 0, stream>>>(GF_f, focal_idx, MAPS, M, centerline, L,
                                      cl_W, cl_b, fc1_W, fc1_b, fc2_W, fc2_b,
                                      fco_W, fco_b, (float*)d_out);
}